// Round 8
// baseline (52.930 us; speedup 1.0000x reference)
//
#include <hip/hip_runtime.h>
#include <math.h>

// WindingEmbedding: rows = 32768 (B=8, S=4096), D=1024, W=8 windings, F=16 feats.
// out[row][d] = ((emb - mu) * rsqrt(var+eps)) * gamma + beta
// emb[row][d] = sum_f feats[row][f] * pw[d][f] + pb[d]
//
// Analytic LayerNorm stats (no reduction over D):
//   mu     = f . meanW + mean_b
//   E[e^2] = f' M f + 2 f . c + mean_b2,  var = E[e^2] - mu^2
// with M = (1/D) W'W (16x16), meanW = (1/D) W'1, c = (1/D) W'b.
//
// TWO kernels only (R7 lesson: each extra dispatch costs ~5-10us of gap):
//   stats_partial: 16 blocks, block b reduces pw rows [64b, 64b+64) -> partials.
//   wind_main: every block sums the 16 partials itself (16 L2-hit loads/thread,
//   overlapped with weight/feat staging, reusing the existing barrier).
// wind_main: 1 dim/thread (16-float weight row in regs -> low VGPR, high
// occupancy), per-row stats via 16-lane in-wave shuffle, 2 barriers total.

#define TWO_PI 6.28318530717958647692f
#define INV_VOCAB (1.0f / 50257.0f)
#define INV_D (1.0f / 1024.0f)
#define ROWS_PB 32
#define PSTRIDE 320
#define NPART 16

typedef float f32x4 __attribute__((ext_vector_type(4)));

// ---------- stats partial: 16 blocks, block b covers d in [64b, 64b+64) ----------
__global__ __launch_bounds__(256) void stats_partial(const float* __restrict__ pw,
                                                     const float* __restrict__ pb,
                                                     float* __restrict__ ws) {
  const int t = threadIdx.x;
  const int b = blockIdx.x;
  const int f = t >> 4, g = t & 15;
  const int d0 = b * 64;

  float m = 0.f, mw = 0.f, cc = 0.f, b1 = 0.f, b2 = 0.f;
#pragma unroll 8
  for (int k = 0; k < 64; ++k) {
    const int d = d0 + k;
    const float wf = pw[d * 16 + f];
    const float wg = pw[d * 16 + g];
    m = fmaf(wf, wg, m);
    if (g == 0) {
      const float bb = pb[d];
      mw += wf;
      cc = fmaf(wf, bb, cc);
      if (f == 0) {
        b1 += bb;
        b2 = fmaf(bb, bb, b2);
      }
    }
  }
  float* p = ws + b * PSTRIDE;
  p[t] = m * INV_D;
  if (g == 0) {
    p[256 + f] = mw * INV_D;
    p[272 + f] = cc * INV_D;
    if (f == 0) {
      p[288] = b1 * INV_D;
      p[289] = b2 * INV_D;
    }
  }
}

// ---------- main: grid (4 dim-blocks, 1024 row-blocks), 256 thr ----------
__global__ __launch_bounds__(256) void wind_main(const int* __restrict__ x,
                                                 const float* __restrict__ winds,
                                                 const float* __restrict__ pw,
                                                 const float* __restrict__ pb,
                                                 const float* __restrict__ gamma,
                                                 const float* __restrict__ beta,
                                                 const float* __restrict__ ws,
                                                 float* __restrict__ out) {
  __shared__ __align__(16) float feat[ROWS_PB][20];  // stride 20: 16B-aligned, <=2-way
  __shared__ __align__(16) float Mlds[16][20];       // stride 20: b128-loadable rows
  __shared__ float mwl[16], cl[16], cst[2];
  __shared__ float murs[ROWS_PB][2];

  const int tid = threadIdx.x;
  const int d = blockIdx.x * 256 + tid;  // this thread's single output dim
  const int row0 = blockIdx.y * ROWS_PB;

  // ---- fold the stats reduce into this block: sum 16 partials (L2-hit) ----
  {
    float accM = 0.f;
#pragma unroll
    for (int b = 0; b < NPART; ++b) accM += ws[b * PSTRIDE + tid];
    Mlds[tid >> 4][tid & 15] = accM;
    if (tid < 34) {
      float acc2 = 0.f;
#pragma unroll
      for (int b = 0; b < NPART; ++b) acc2 += ws[b * PSTRIDE + 256 + tid];
      if (tid < 16) mwl[tid] = acc2;
      else if (tid < 32) cl[tid - 16] = acc2;
      else cst[tid - 32] = acc2;
    }
  }

  // this dim's projection row + bias/affine
  const f32x4 w0 = reinterpret_cast<const f32x4*>(pw)[d * 4 + 0];
  const f32x4 w1 = reinterpret_cast<const f32x4*>(pw)[d * 4 + 1];
  const f32x4 w2 = reinterpret_cast<const f32x4*>(pw)[d * 4 + 2];
  const f32x4 w3 = reinterpret_cast<const f32x4*>(pw)[d * 4 + 3];
  const float pbd = pb[d];
  const float gd = gamma[d];
  const float bd = beta[d];

  // feature tile: 32 rows x 16 feats, 2 slots (sincos) per thread
#pragma unroll
  for (int s = 0; s < 2; ++s) {
    const int slot = tid + s * 256;
    const int r = slot >> 4, jj = slot & 15;
    const float tf = (float)x[row0 + r] * INV_VOCAB;
    float sn, cs;
    sincosf(TWO_PI * tf * winds[jj >> 1], &sn, &cs);
    feat[r][jj] = (jj & 1) ? sn : cs;  // [cos0,sin0,cos1,sin1,...]
  }
  __syncthreads();

  // per-row stats: 16-lane group per row, 2 rows per thread, in-wave shuffle
  {
    const int jj = tid & 15;
    const float mwj = mwl[jj];
    const float cj = cl[jj];
    const f32x4 M0 = *reinterpret_cast<const f32x4*>(&Mlds[jj][0]);
    const f32x4 M1 = *reinterpret_cast<const f32x4*>(&Mlds[jj][4]);
    const f32x4 M2 = *reinterpret_cast<const f32x4*>(&Mlds[jj][8]);
    const f32x4 M3 = *reinterpret_cast<const f32x4*>(&Mlds[jj][12]);
#pragma unroll
    for (int h = 0; h < 2; ++h) {
      const int r = (tid >> 4) + h * 16;
      const f32x4 F0 = *reinterpret_cast<const f32x4*>(&feat[r][0]);
      const f32x4 F1 = *reinterpret_cast<const f32x4*>(&feat[r][4]);
      const f32x4 F2 = *reinterpret_cast<const f32x4*>(&feat[r][8]);
      const f32x4 F3 = *reinterpret_cast<const f32x4*>(&feat[r][12]);
      float acc = 0.f;
      acc = fmaf(M0.x, F0.x, acc); acc = fmaf(M0.y, F0.y, acc);
      acc = fmaf(M0.z, F0.z, acc); acc = fmaf(M0.w, F0.w, acc);
      acc = fmaf(M1.x, F1.x, acc); acc = fmaf(M1.y, F1.y, acc);
      acc = fmaf(M1.z, F1.z, acc); acc = fmaf(M1.w, F1.w, acc);
      acc = fmaf(M2.x, F2.x, acc); acc = fmaf(M2.y, F2.y, acc);
      acc = fmaf(M2.z, F2.z, acc); acc = fmaf(M2.w, F2.w, acc);
      acc = fmaf(M3.x, F3.x, acc); acc = fmaf(M3.y, F3.y, acc);
      acc = fmaf(M3.z, F3.z, acc); acc = fmaf(M3.w, F3.w, acc);
      const float fjj = feat[r][jj];  // scalar LDS read (<=2-way)
      float pE = fjj * fmaf(2.f, cj, acc);
      float pM = fjj * mwj;
#pragma unroll
      for (int off = 1; off < 16; off <<= 1) {
        pE += __shfl_xor(pE, off);
        pM += __shfl_xor(pM, off);
      }
      if (jj == 0) {
        const float mu = pM + cst[0];
        const float var = (pE + cst[1]) - mu * mu;
        murs[r][0] = mu;
        murs[r][1] = rsqrtf(var + 1e-5f);
      }
    }
  }
  __syncthreads();

  // main loop: 32 rows, 16 FMA + 1 coalesced dword store each; no barriers
  float* o = out + (size_t)row0 * 1024 + d;
#pragma unroll 2
  for (int r = 0; r < ROWS_PB; ++r) {
    const f32x4 F0 = *reinterpret_cast<const f32x4*>(&feat[r][0]);
    const f32x4 F1 = *reinterpret_cast<const f32x4*>(&feat[r][4]);
    const f32x4 F2 = *reinterpret_cast<const f32x4*>(&feat[r][8]);
    const f32x4 F3 = *reinterpret_cast<const f32x4*>(&feat[r][12]);
    float e = pbd;
    e = fmaf(w0.x, F0.x, e); e = fmaf(w0.y, F0.y, e);
    e = fmaf(w0.z, F0.z, e); e = fmaf(w0.w, F0.w, e);
    e = fmaf(w1.x, F1.x, e); e = fmaf(w1.y, F1.y, e);
    e = fmaf(w1.z, F1.z, e); e = fmaf(w1.w, F1.w, e);
    e = fmaf(w2.x, F2.x, e); e = fmaf(w2.y, F2.y, e);
    e = fmaf(w2.z, F2.z, e); e = fmaf(w2.w, F2.w, e);
    e = fmaf(w3.x, F3.x, e); e = fmaf(w3.y, F3.y, e);
    e = fmaf(w3.z, F3.z, e); e = fmaf(w3.w, F3.w, e);
    const float mu = murs[r][0];
    const float rs = murs[r][1];
    const float a = rs * gd;
    o[(size_t)r * 1024] = fmaf(e, a, fmaf(-mu, a, bd));
  }
}

extern "C" void kernel_launch(void* const* d_in, const int* in_sizes, int n_in,
                              void* d_out, int out_size, void* d_ws, size_t ws_size,
                              hipStream_t stream) {
  const int* x = (const int*)d_in[0];
  const float* winds = (const float*)d_in[1];
  const float* pw = (const float*)d_in[2];
  const float* pb = (const float*)d_in[3];
  const float* gamma = (const float*)d_in[4];
  const float* beta = (const float*)d_in[5];
  float* out = (float*)d_out;
  float* ws = (float*)d_ws;

  const int rows = in_sizes[0];  // 32768
  stats_partial<<<NPART, 256, 0, stream>>>(pw, pb, ws);
  dim3 grid(4, (unsigned)(rows / ROWS_PB));
  wind_main<<<grid, 256, 0, stream>>>(x, winds, pw, pb, gamma, beta, ws, out);
}

// Round 9
// 52.077 us; speedup vs baseline: 1.0164x; 1.0164x over previous
//
#include <hip/hip_runtime.h>
#include <math.h>

// WindingEmbedding: rows = 32768 (B=8, S=4096), D=1024, W=8 windings, F=16 feats.
// out[row][d] = ((emb - mu) * rsqrt(var+eps)) * gamma + beta
// emb[row][d] = sum_f feats[row][f] * pw[d][f] + pb[d]
//
// Analytic LayerNorm stats (no reduction over D):
//   mu     = f . meanW + mean_b
//   E[e^2] = f' M f + 2 f . c + mean_b2,  var = E[e^2] - mu^2
// with M = (1/D) W'W (16x16), meanW = (1/D) W'1, c = (1/D) W'b.
//
// TWO dispatches (R7: 3 dispatches cost ~12us of gaps; R8: letting every main
// block read 20KB of cross-XCD partials cost +10us):
//   stats_all: 64 blocks write partials; block 0 spins on agent-scope flags,
//              reduces in fixed order (deterministic), resets flags for replay.
//   wind_main: reads only the 1.2KB finals per block; 1 dim/thread, 64 rows/blk,
//              2 barriers, nontemporal coalesced stores.

#define TWO_PI 6.28318530717958647692f
#define INV_VOCAB (1.0f / 50257.0f)
#define INV_D (1.0f / 1024.0f)
#define ROWS_PB 64
#define PSTRIDE 320
#define NPART 64
#define FINAL_OFF 20480   // float index of finals
#define FLAG_OFF 20800    // uint index of flags
#define FLAG_MAGIC 0x5A5A5A5Au

typedef float f32x4 __attribute__((ext_vector_type(4)));

// ---------- stats: partials + in-kernel deterministic reduce ----------
__global__ __launch_bounds__(256) void stats_all(const float* __restrict__ pw,
                                                 const float* __restrict__ pb,
                                                 float* __restrict__ ws) {
  const int t = threadIdx.x;
  const int b = blockIdx.x;  // covers d in [16b, 16b+16)
  const int f = t >> 4, g = t & 15;
  const int d0 = b * 16;

  float m = 0.f, mw = 0.f, cc = 0.f, b1 = 0.f, b2 = 0.f;
#pragma unroll
  for (int k = 0; k < 16; ++k) {
    const int d = d0 + k;
    const float wf = pw[d * 16 + f];
    const float wg = pw[d * 16 + g];
    m = fmaf(wf, wg, m);
    if (g == 0) {
      const float bb = pb[d];
      mw += wf;
      cc = fmaf(wf, bb, cc);
      if (f == 0) {
        b1 += bb;
        b2 = fmaf(bb, bb, b2);
      }
    }
  }
  float* p = ws + b * PSTRIDE;
  p[t] = m * INV_D;
  if (g == 0) {
    p[256 + f] = mw * INV_D;
    p[272 + f] = cc * INV_D;
    if (f == 0) {
      p[288] = b1 * INV_D;
      p[289] = b2 * INV_D;
    }
  }

  unsigned* flags = reinterpret_cast<unsigned*>(ws) + FLAG_OFF;
  __syncthreads();   // all partial stores of this block issued & drained
  __threadfence();   // device-scope release of the partials
  if (t == 0)
    __hip_atomic_store(&flags[b], FLAG_MAGIC, __ATOMIC_RELEASE,
                       __HIP_MEMORY_SCOPE_AGENT);

  if (b == 0) {
    // lanes 0..63 each watch one flag; producers never wait -> no deadlock
    if (t < NPART) {
      while (__hip_atomic_load(&flags[t], __ATOMIC_ACQUIRE,
                               __HIP_MEMORY_SCOPE_AGENT) != FLAG_MAGIC) {
      }
    }
    __syncthreads();
    __threadfence();  // acquire: invalidate stale lines before partial reads
    float s = 0.f;
#pragma unroll
    for (int bb = 0; bb < NPART; ++bb) s += ws[bb * PSTRIDE + t];
    ws[FINAL_OFF + t] = s;
    if (t < 34) {
      float s2 = 0.f;
#pragma unroll
      for (int bb = 0; bb < NPART; ++bb) s2 += ws[bb * PSTRIDE + 256 + t];
      ws[FINAL_OFF + 256 + t] = s2;
    }
    __syncthreads();
    if (t < NPART) flags[t] = 0u;  // reset for next graph replay
    __threadfence();
  }
}

// ---------- main: grid (4 dim-blocks, 512 row-blocks), 256 thr ----------
__global__ __launch_bounds__(256) void wind_main(const int* __restrict__ x,
                                                 const float* __restrict__ winds,
                                                 const float* __restrict__ pw,
                                                 const float* __restrict__ pb,
                                                 const float* __restrict__ gamma,
                                                 const float* __restrict__ beta,
                                                 const float* __restrict__ ws,
                                                 float* __restrict__ out) {
  __shared__ __align__(16) float feat[ROWS_PB][20];  // stride 20: 16B-aligned, <=2-way
  __shared__ __align__(16) float Mlds[16][20];       // stride 20: b128-loadable rows
  __shared__ float mwl[16], cl[16], cst[2];
  __shared__ float murs[ROWS_PB][2];

  const int tid = threadIdx.x;
  const int d = blockIdx.x * 256 + tid;  // this thread's single output dim
  const int row0 = blockIdx.y * ROWS_PB;

  // stage analytic-stats constants (finals only: 1.2 KB)
  Mlds[tid >> 4][tid & 15] = ws[FINAL_OFF + tid];
  if (tid < 16) mwl[tid] = ws[FINAL_OFF + 256 + tid];
  else if (tid < 32) cl[tid - 16] = ws[FINAL_OFF + 256 + tid - 16 + 16];
  else if (tid < 34) cst[tid - 32] = ws[FINAL_OFF + 256 + tid];

  // this dim's projection row + bias/affine
  const f32x4 w0 = reinterpret_cast<const f32x4*>(pw)[d * 4 + 0];
  const f32x4 w1 = reinterpret_cast<const f32x4*>(pw)[d * 4 + 1];
  const f32x4 w2 = reinterpret_cast<const f32x4*>(pw)[d * 4 + 2];
  const f32x4 w3 = reinterpret_cast<const f32x4*>(pw)[d * 4 + 3];
  const float pbd = pb[d];
  const float gd = gamma[d];
  const float bd = beta[d];

  // feature tile: 64 rows x 16 feats, 4 slots (sincos) per thread
#pragma unroll
  for (int s = 0; s < 4; ++s) {
    const int slot = tid + s * 256;
    const int r = slot >> 4, jj = slot & 15;
    const float tf = (float)x[row0 + r] * INV_VOCAB;
    float sn, cs;
    sincosf(TWO_PI * tf * winds[jj >> 1], &sn, &cs);
    feat[r][jj] = (jj & 1) ? sn : cs;  // [cos0,sin0,cos1,sin1,...]
  }
  __syncthreads();

  // per-row stats: 16-lane group per row, 4 rows per thread, in-wave shuffle
  {
    const int jj = tid & 15;
    const float mwj = mwl[jj];
    const float cj = cl[jj];
    const f32x4 M0 = *reinterpret_cast<const f32x4*>(&Mlds[jj][0]);
    const f32x4 M1 = *reinterpret_cast<const f32x4*>(&Mlds[jj][4]);
    const f32x4 M2 = *reinterpret_cast<const f32x4*>(&Mlds[jj][8]);
    const f32x4 M3 = *reinterpret_cast<const f32x4*>(&Mlds[jj][12]);
#pragma unroll
    for (int h = 0; h < 4; ++h) {
      const int r = (tid >> 4) + h * 16;
      const f32x4 F0 = *reinterpret_cast<const f32x4*>(&feat[r][0]);
      const f32x4 F1 = *reinterpret_cast<const f32x4*>(&feat[r][4]);
      const f32x4 F2 = *reinterpret_cast<const f32x4*>(&feat[r][8]);
      const f32x4 F3 = *reinterpret_cast<const f32x4*>(&feat[r][12]);
      float acc = 0.f;
      acc = fmaf(M0.x, F0.x, acc); acc = fmaf(M0.y, F0.y, acc);
      acc = fmaf(M0.z, F0.z, acc); acc = fmaf(M0.w, F0.w, acc);
      acc = fmaf(M1.x, F1.x, acc); acc = fmaf(M1.y, F1.y, acc);
      acc = fmaf(M1.z, F1.z, acc); acc = fmaf(M1.w, F1.w, acc);
      acc = fmaf(M2.x, F2.x, acc); acc = fmaf(M2.y, F2.y, acc);
      acc = fmaf(M2.z, F2.z, acc); acc = fmaf(M2.w, F2.w, acc);
      acc = fmaf(M3.x, F3.x, acc); acc = fmaf(M3.y, F3.y, acc);
      acc = fmaf(M3.z, F3.z, acc); acc = fmaf(M3.w, F3.w, acc);
      const float fjj = feat[r][jj];  // scalar LDS read (<=2-way)
      float pE = fjj * fmaf(2.f, cj, acc);
      float pM = fjj * mwj;
#pragma unroll
      for (int off = 1; off < 16; off <<= 1) {
        pE += __shfl_xor(pE, off);
        pM += __shfl_xor(pM, off);
      }
      if (jj == 0) {
        const float mu = pM + cst[0];
        const float var = (pE + cst[1]) - mu * mu;
        murs[r][0] = mu;
        murs[r][1] = rsqrtf(var + 1e-5f);
      }
    }
  }
  __syncthreads();

  // main loop: 64 rows, 16 FMA + 1 coalesced nontemporal dword store each
  float* o = out + (size_t)row0 * 1024 + d;
#pragma unroll 2
  for (int r = 0; r < ROWS_PB; ++r) {
    const f32x4 F0 = *reinterpret_cast<const f32x4*>(&feat[r][0]);
    const f32x4 F1 = *reinterpret_cast<const f32x4*>(&feat[r][4]);
    const f32x4 F2 = *reinterpret_cast<const f32x4*>(&feat[r][8]);
    const f32x4 F3 = *reinterpret_cast<const f32x4*>(&feat[r][12]);
    float e = pbd;
    e = fmaf(w0.x, F0.x, e); e = fmaf(w0.y, F0.y, e);
    e = fmaf(w0.z, F0.z, e); e = fmaf(w0.w, F0.w, e);
    e = fmaf(w1.x, F1.x, e); e = fmaf(w1.y, F1.y, e);
    e = fmaf(w1.z, F1.z, e); e = fmaf(w1.w, F1.w, e);
    e = fmaf(w2.x, F2.x, e); e = fmaf(w2.y, F2.y, e);
    e = fmaf(w2.z, F2.z, e); e = fmaf(w2.w, F2.w, e);
    e = fmaf(w3.x, F3.x, e); e = fmaf(w3.y, F3.y, e);
    e = fmaf(w3.z, F3.z, e); e = fmaf(w3.w, F3.w, e);
    const float mu = murs[r][0];
    const float rs = murs[r][1];
    const float a = rs * gd;
    __builtin_nontemporal_store(fmaf(e, a, fmaf(-mu, a, bd)),
                                o + (size_t)r * 1024);
  }
}

extern "C" void kernel_launch(void* const* d_in, const int* in_sizes, int n_in,
                              void* d_out, int out_size, void* d_ws, size_t ws_size,
                              hipStream_t stream) {
  const int* x = (const int*)d_in[0];
  const float* winds = (const float*)d_in[1];
  const float* pw = (const float*)d_in[2];
  const float* pb = (const float*)d_in[3];
  const float* gamma = (const float*)d_in[4];
  const float* beta = (const float*)d_in[5];
  float* out = (float*)d_out;
  float* ws = (float*)d_ws;

  const int rows = in_sizes[0];  // 32768
  stats_all<<<NPART, 256, 0, stream>>>(pw, pb, ws);
  dim3 grid(4, (unsigned)(rows / ROWS_PB));
  wind_main<<<grid, 256, 0, stream>>>(x, winds, pw, pb, gamma, beta, ws, out);
}

// Round 10
// 41.008 us; speedup vs baseline: 1.2907x; 1.2699x over previous
//
#include <hip/hip_runtime.h>
#include <math.h>

// WindingEmbedding: rows = 32768 (B=8, S=4096), D=1024, W=8 windings, F=16 feats.
// out[row][d] = ((emb - mu) * rsqrt(var+eps)) * gamma + beta
// emb[row][d] = sum_f feats[row][f] * pw[d][f] + pb[d]
//
// Analytic LayerNorm stats (no reduction over D):
//   mu     = f . meanW + mean_b
//   E[e^2] = f' M f + 2 f . c + mean_b2,  var = E[e^2] - mu^2
// with M = (1/D) W'W (16x16), meanW = (1/D) W'1, c = (1/D) W'b.
//
// R10 structure: R7's proven 3-dispatch stats chain (parallel partial + tiny
// reduce; single-block stats is a 95us latency chain, R6) + a 4-dims/thread
// main kernel. 1 dim/thread (R7) was LDS-return-BW-bound: 2GB of broadcast
// ds_read_b128 (~14us/CU). 4 dims/thread amortizes the 64B/row feat read over
// 4 output dims -> 512MB LDS traffic, float4 stores. Regular stores only
// (nontemporal regressed in R5/R9). No min-waves clamp (R5 lesson).

#define TWO_PI 6.28318530717958647692f
#define INV_VOCAB (1.0f / 50257.0f)
#define INV_D (1.0f / 1024.0f)
#define ROWS_PB 32
#define PSTRIDE 320
#define FINAL_OFF 20480

typedef float f32x4 __attribute__((ext_vector_type(4)));

// ---------- stats partial: 64 blocks, block b covers d in [16b, 16b+16) ----------
__global__ __launch_bounds__(256) void stats_partial(const float* __restrict__ pw,
                                                     const float* __restrict__ pb,
                                                     float* __restrict__ ws) {
  const int t = threadIdx.x;
  const int b = blockIdx.x;
  const int f = t >> 4, g = t & 15;
  const int d0 = b * 16;

  float m = 0.f, mw = 0.f, cc = 0.f, b1 = 0.f, b2 = 0.f;
#pragma unroll
  for (int k = 0; k < 16; ++k) {
    const int d = d0 + k;
    const float wf = pw[d * 16 + f];
    const float wg = pw[d * 16 + g];
    m = fmaf(wf, wg, m);
    if (g == 0) {
      const float bb = pb[d];
      mw += wf;
      cc = fmaf(wf, bb, cc);
      if (f == 0) {
        b1 += bb;
        b2 = fmaf(bb, bb, b2);
      }
    }
  }
  float* p = ws + b * PSTRIDE;
  p[t] = m * INV_D;
  if (g == 0) {
    p[256 + f] = mw * INV_D;
    p[272 + f] = cc * INV_D;
    if (f == 0) {
      p[288] = b1 * INV_D;
      p[289] = b2 * INV_D;
    }
  }
}

// ---------- stats reduce: 1 block, 320 threads, 64 partials each ----------
__global__ __launch_bounds__(320) void stats_reduce(float* __restrict__ ws) {
  const int t = threadIdx.x;  // only 0..289 meaningful
  float s = 0.f;
#pragma unroll
  for (int b = 0; b < 64; ++b) s += ws[b * PSTRIDE + t];
  ws[FINAL_OFF + t] = s;
}

// ---------- main: 1024 row-blocks, 256 thr, 4 dims/thread ----------
__global__ __launch_bounds__(256) void wind_main(const int* __restrict__ x,
                                                 const float* __restrict__ winds,
                                                 const float* __restrict__ pw,
                                                 const float* __restrict__ pb,
                                                 const float* __restrict__ gamma,
                                                 const float* __restrict__ beta,
                                                 const float* __restrict__ ws,
                                                 float* __restrict__ out) {
  __shared__ __align__(16) float feat[ROWS_PB][20];  // stride 20: 16B-aligned, <=2-way
  __shared__ __align__(16) float Mlds[16][20];       // b128-loadable rows
  __shared__ float mwl[16], cl[16], cst[2];
  __shared__ float murs[ROWS_PB][2];

  const int tid = threadIdx.x;
  const int row0 = blockIdx.x * ROWS_PB;

  // stage analytic-stats finals (1.2 KB; ws points at finals)
  Mlds[tid >> 4][tid & 15] = ws[tid];
  if (tid < 16) mwl[tid] = ws[256 + tid];
  else if (tid < 32) cl[tid - 16] = ws[256 + tid];
  else if (tid < 34) cst[tid - 32] = ws[256 + tid];

  // this thread's 4 projection rows (dims 4t..4t+3) + bias/affine
  float4 wreg[4][4];
#pragma unroll
  for (int r = 0; r < 4; ++r)
#pragma unroll
    for (int c = 0; c < 4; ++c)
      wreg[r][c] = reinterpret_cast<const float4*>(pw)[(tid * 4 + r) * 4 + c];
  const float4 pbv = reinterpret_cast<const float4*>(pb)[tid];
  const float4 gv = reinterpret_cast<const float4*>(gamma)[tid];
  const float4 bv = reinterpret_cast<const float4*>(beta)[tid];

  // feature tile: 32 rows x 16 feats, 2 slots (sincos) per thread
#pragma unroll
  for (int s = 0; s < 2; ++s) {
    const int slot = tid + s * 256;
    const int r = slot >> 4, jj = slot & 15;
    const float tf = (float)x[row0 + r] * INV_VOCAB;
    float sn, cs;
    sincosf(TWO_PI * tf * winds[jj >> 1], &sn, &cs);
    feat[r][jj] = (jj & 1) ? sn : cs;  // [cos0,sin0,cos1,sin1,...]
  }
  __syncthreads();

  // per-row stats: 16-lane group per row, 2 rows per thread, in-wave shuffle
  {
    const int jj = tid & 15;
    const float mwj = mwl[jj];
    const float cj = cl[jj];
    const f32x4 M0 = *reinterpret_cast<const f32x4*>(&Mlds[jj][0]);
    const f32x4 M1 = *reinterpret_cast<const f32x4*>(&Mlds[jj][4]);
    const f32x4 M2 = *reinterpret_cast<const f32x4*>(&Mlds[jj][8]);
    const f32x4 M3 = *reinterpret_cast<const f32x4*>(&Mlds[jj][12]);
#pragma unroll
    for (int h = 0; h < 2; ++h) {
      const int r = (tid >> 4) + h * 16;
      const f32x4 F0 = *reinterpret_cast<const f32x4*>(&feat[r][0]);
      const f32x4 F1 = *reinterpret_cast<const f32x4*>(&feat[r][4]);
      const f32x4 F2 = *reinterpret_cast<const f32x4*>(&feat[r][8]);
      const f32x4 F3 = *reinterpret_cast<const f32x4*>(&feat[r][12]);
      float acc = 0.f;
      acc = fmaf(M0.x, F0.x, acc); acc = fmaf(M0.y, F0.y, acc);
      acc = fmaf(M0.z, F0.z, acc); acc = fmaf(M0.w, F0.w, acc);
      acc = fmaf(M1.x, F1.x, acc); acc = fmaf(M1.y, F1.y, acc);
      acc = fmaf(M1.z, F1.z, acc); acc = fmaf(M1.w, F1.w, acc);
      acc = fmaf(M2.x, F2.x, acc); acc = fmaf(M2.y, F2.y, acc);
      acc = fmaf(M2.z, F2.z, acc); acc = fmaf(M2.w, F2.w, acc);
      acc = fmaf(M3.x, F3.x, acc); acc = fmaf(M3.y, F3.y, acc);
      acc = fmaf(M3.z, F3.z, acc); acc = fmaf(M3.w, F3.w, acc);
      const float fjj = feat[r][jj];
      float pE = fjj * fmaf(2.f, cj, acc);
      float pM = fjj * mwj;
#pragma unroll
      for (int off = 1; off < 16; off <<= 1) {
        pE += __shfl_xor(pE, off);
        pM += __shfl_xor(pM, off);
      }
      if (jj == 0) {
        const float mu = pM + cst[0];
        const float var = (pE + cst[1]) - mu * mu;
        murs[r][0] = mu;
        murs[r][1] = rsqrtf(var + 1e-5f);
      }
    }
  }
  __syncthreads();

  // main loop: 32 rows x 4 dims/thread; broadcast feat reads, float4 stores
  float* o = out + (size_t)row0 * 1024 + tid * 4;
#pragma unroll 2
  for (int r = 0; r < ROWS_PB; ++r) {
    const f32x4 F0 = *reinterpret_cast<const f32x4*>(&feat[r][0]);
    const f32x4 F1 = *reinterpret_cast<const f32x4*>(&feat[r][4]);
    const f32x4 F2 = *reinterpret_cast<const f32x4*>(&feat[r][8]);
    const f32x4 F3 = *reinterpret_cast<const f32x4*>(&feat[r][12]);
    float e[4];
#pragma unroll
    for (int k = 0; k < 4; ++k) {
      float a = (k == 0) ? pbv.x : (k == 1) ? pbv.y : (k == 2) ? pbv.z : pbv.w;
      a = fmaf(wreg[k][0].x, F0.x, a);
      a = fmaf(wreg[k][0].y, F0.y, a);
      a = fmaf(wreg[k][0].z, F0.z, a);
      a = fmaf(wreg[k][0].w, F0.w, a);
      a = fmaf(wreg[k][1].x, F1.x, a);
      a = fmaf(wreg[k][1].y, F1.y, a);
      a = fmaf(wreg[k][1].z, F1.z, a);
      a = fmaf(wreg[k][1].w, F1.w, a);
      a = fmaf(wreg[k][2].x, F2.x, a);
      a = fmaf(wreg[k][2].y, F2.y, a);
      a = fmaf(wreg[k][2].z, F2.z, a);
      a = fmaf(wreg[k][2].w, F2.w, a);
      a = fmaf(wreg[k][3].x, F3.x, a);
      a = fmaf(wreg[k][3].y, F3.y, a);
      a = fmaf(wreg[k][3].z, F3.z, a);
      a = fmaf(wreg[k][3].w, F3.w, a);
      e[k] = a;
    }
    const float mu = murs[r][0];
    const float rs = murs[r][1];
    const float s0 = gv.x * rs, s1 = gv.y * rs, s2 = gv.z * rs, s3 = gv.w * rs;
    f32x4 res;
    res.x = fmaf(e[0], s0, fmaf(-mu, s0, bv.x));
    res.y = fmaf(e[1], s1, fmaf(-mu, s1, bv.y));
    res.z = fmaf(e[2], s2, fmaf(-mu, s2, bv.z));
    res.w = fmaf(e[3], s3, fmaf(-mu, s3, bv.w));
    *reinterpret_cast<f32x4*>(o + (size_t)r * 1024) = res;
  }
}

extern "C" void kernel_launch(void* const* d_in, const int* in_sizes, int n_in,
                              void* d_out, int out_size, void* d_ws, size_t ws_size,
                              hipStream_t stream) {
  const int* x = (const int*)d_in[0];
  const float* winds = (const float*)d_in[1];
  const float* pw = (const float*)d_in[2];
  const float* pb = (const float*)d_in[3];
  const float* gamma = (const float*)d_in[4];
  const float* beta = (const float*)d_in[5];
  float* out = (float*)d_out;
  float* ws = (float*)d_ws;

  const int rows = in_sizes[0];  // 32768
  stats_partial<<<64, 256, 0, stream>>>(pw, pb, ws);
  stats_reduce<<<1, 320, 0, stream>>>(ws);
  wind_main<<<rows / ROWS_PB, 256, 0, stream>>>(x, winds, pw, pb, gamma, beta,
                                                ws + FINAL_OFF, out);
}